// Round 9
// baseline (143.107 us; speedup 1.0000x reference)
//
#include <hip/hip_runtime.h>
#include <stdint.h>

#define NH     16
#define LSEQ   2048
#define DH     64
#define HDIM   1024
#define BATCH  2

typedef __attribute__((ext_vector_type(8))) short bf16x8;
typedef __attribute__((ext_vector_type(8))) unsigned short u16x8;
typedef __attribute__((ext_vector_type(4))) float f32x4;
typedef __attribute__((ext_vector_type(16))) float f32x16;

// fp32 -> bf16 (RNE)
static __device__ inline unsigned short f2bs(float f) {
    union { float f; uint32_t u; } v; v.f = f;
    uint32_t u = v.u;
    return (unsigned short)((u + 0x7FFFu + ((u >> 16) & 1u)) >> 16);
}

static __device__ inline unsigned int cvtpk(float lo, float hi) {
    unsigned int r;
    asm("v_cvt_pk_bf16_f32 %0, %1, %2" : "=v"(r) : "v"(lo), "v"(hi));
    return r;
}
static __device__ inline void pl32swap(unsigned int &a, unsigned int &b) {
    asm volatile("v_permlane32_swap_b32 %0, %1" : "+v"(a), "+v"(b));
}

#define GLOAD_LDS(gp, lp) \
    __builtin_amdgcn_global_load_lds((const __attribute__((address_space(1))) void*)(gp), \
                                     (__attribute__((address_space(3))) void*)(lp), 16, 0, 0)

#define MFMA32(A, B, C) __builtin_amdgcn_mfma_f32_32x32x16_bf16((A), (B), (C), 0, 0, 0)

// sqrt(0.125 * log2(e)) — folded into xb so (sQ)·(sK) carries the softmax scale
#define QK_SCALE 0.42466083f

// ---------------------------------------------------------------------------
// Kernel 1: prep (unchanged from r17 — verified with the frag-major layouts).
// ---------------------------------------------------------------------------
__global__ __launch_bounds__(256) void prep_kernel(const float* __restrict__ x,
                                                   const float* __restrict__ W,
                                                   unsigned short* __restrict__ xb,
                                                   unsigned short* __restrict__ xt,
                                                   unsigned short* __restrict__ wbt) {
    const int lt = blockIdx.x, bh = blockIdx.y;
    const int bid = bh * 32 + lt;
    const int t = threadIdx.x;

    if (t < 128) {
        const int gid = bid * 128 + t;
        const int n  = gid >> 7;
        const int kc = gid & 127;
        const float* src = W + (size_t)n * 1024 + kc * 8;
        float4 f0 = *(const float4*)(src);
        float4 f1 = *(const float4*)(src + 4);
        u16x8 v;
        v[0]=f2bs(f0.x); v[1]=f2bs(f0.y); v[2]=f2bs(f0.z); v[3]=f2bs(f0.w);
        v[4]=f2bs(f1.x); v[5]=f2bs(f1.y); v[6]=f2bs(f1.z); v[7]=f2bs(f1.w);
        const int nt = n >> 7, rn = n & 127;
        const int kt = kc >> 3, c = kc & 7;
        *(u16x8*)(wbt + (((size_t)nt * 16 + kt) * 128 + rn) * 64 + ((c ^ (rn & 7)) * 8)) = v;
    }

    const int b = bh >> 4, h = bh & 15;
    const int r = t >> 2, cp = t & 3;

    __shared__ __align__(16) unsigned short Sm[64][72];

    const float* src = x + ((size_t)(b * LSEQ + lt * 64 + r)) * HDIM + h * DH + cp * 16;
    float4 f0 = *(const float4*)(src);
    float4 f1 = *(const float4*)(src + 4);
    float4 f2 = *(const float4*)(src + 8);
    float4 f3 = *(const float4*)(src + 12);
    u16x8 lo, hi;
    lo[0]=f2bs(f0.x); lo[1]=f2bs(f0.y); lo[2]=f2bs(f0.z); lo[3]=f2bs(f0.w);
    lo[4]=f2bs(f1.x); lo[5]=f2bs(f1.y); lo[6]=f2bs(f1.z); lo[7]=f2bs(f1.w);
    hi[0]=f2bs(f2.x); hi[1]=f2bs(f2.y); hi[2]=f2bs(f2.z); hi[3]=f2bs(f2.w);
    hi[4]=f2bs(f3.x); hi[5]=f2bs(f3.y); hi[6]=f2bs(f3.z); hi[7]=f2bs(f3.w);
    u16x8 slo, shi;
    slo[0]=f2bs(f0.x*QK_SCALE); slo[1]=f2bs(f0.y*QK_SCALE); slo[2]=f2bs(f0.z*QK_SCALE); slo[3]=f2bs(f0.w*QK_SCALE);
    slo[4]=f2bs(f1.x*QK_SCALE); slo[5]=f2bs(f1.y*QK_SCALE); slo[6]=f2bs(f1.z*QK_SCALE); slo[7]=f2bs(f1.w*QK_SCALE);
    shi[0]=f2bs(f2.x*QK_SCALE); shi[1]=f2bs(f2.y*QK_SCALE); shi[2]=f2bs(f2.z*QK_SCALE); shi[3]=f2bs(f2.w*QK_SCALE);
    shi[4]=f2bs(f3.x*QK_SCALE); shi[5]=f2bs(f3.y*QK_SCALE); shi[6]=f2bs(f3.z*QK_SCALE); shi[7]=f2bs(f3.w*QK_SCALE);

    {   // xb frag-major: st = lt*2 + (r>>5); ds = cp; lane = hh*32 + (r&31)
        unsigned short* xbase = xb + (size_t)bh * 131072
                              + ((size_t)lt * 2 + (r >> 5)) * 2048 + cp * 512 + (r & 31) * 8;
        *(u16x8*)(xbase)       = slo;   // hh=0 (d = cp*16 + 0..7)
        *(u16x8*)(xbase + 256) = shi;   // hh=1 (d = cp*16 + 8..15)
    }
    *(u16x8*)&Sm[r][cp * 16]     = lo;
    *(u16x8*)&Sm[r][cp * 16 + 8] = hi;
    __syncthreads();

    {   // xt frag-major: tile = lt; side = d>>5; ks = part>>4; lane = hh*32 + (d&31)
        const int d = t >> 2, part = (t & 3) * 16;
        unsigned short* vbase = xt + (size_t)bh * 131072 + (size_t)lt * 4096
                              + (d >> 5) * 2048 + (part >> 4) * 512 + (d & 31) * 8;
        u16x8 g0, g1;
        #pragma unroll
        for (int i = 0; i < 8; ++i) g0[i] = Sm[part + i][d];
        #pragma unroll
        for (int i = 0; i < 8; ++i) g1[i] = Sm[part + 8 + i][d];
        *(u16x8*)(vbase)       = g0;   // kv part..part+7   (hh=0)
        *(u16x8*)(vbase + 256) = g1;   // kv part+8..part+15 (hh=1)
    }
}

// ---------------------------------------------------------------------------
// Kernel 2: flash attention, 32x32 MFMA, zero LDS / zero barriers.
// r18: register double-buffered K (prefetch K(t+1) before computing on K(t))
// + early-issued V (latency covered by exp2+pack) — removes the exposed
// per-iteration vmem round trip that kept r12..r17 all at 55-60us.
// Unroll-by-2 with NAMED buffers (static indexing, no scratch).
// grid (32 bh, 16 qt) = 512 blocks, 256 thr (4 waves x 32 q-rows).
// ---------------------------------------------------------------------------
__device__ __forceinline__ void attn_iter(int tt,
                                          const char* xbB, const char* xtB, int lane,
                                          bf16x8 (&kca)[4], bf16x8 (&kcb)[4],
                                          bf16x8 (&kna)[4], bf16x8 (&knb)[4],
                                          const bf16x8 (&qf)[4], const bf16x8 &ones,
                                          f32x16 &accA, f32x16 &accB, f32x16 &accS) {
    // --- prefetch K(tt+1) into the alternate buffer (consumed next iter) ---
    if (tt + 1 < 32) {
        const char* kp = xbB + (size_t)(tt + 1) * 8192 + lane * 16;
        #pragma unroll
        for (int ds = 0; ds < 4; ++ds) {
            kna[ds] = *(const bf16x8*)(kp + ds * 1024);
            knb[ds] = *(const bf16x8*)(kp + 4096 + ds * 1024);
        }
    }
    // --- issue V(tt) now; consumed after exp2+pack (~400cy later) ---
    bf16x8 vfa[4], vfb[4];
    {
        const char* vp = xtB + (size_t)tt * 8192 + lane * 16;
        #pragma unroll
        for (int ks = 0; ks < 4; ++ks) {
            vfa[ks] = *(const bf16x8*)(vp + ks * 1024);
            vfb[ks] = *(const bf16x8*)(vp + 4096 + ks * 1024);
        }
    }

    // --- QK on the already-resident K(tt): S^T[kv][q] ---
    f32x16 s0, s1;
    #pragma unroll
    for (int r = 0; r < 16; ++r) { s0[r] = 0.f; s1[r] = 0.f; }
    __builtin_amdgcn_s_setprio(1);
    #pragma unroll
    for (int ds = 0; ds < 4; ++ds) {
        s0 = MFMA32(kca[ds], qf[ds], s0);
        s1 = MFMA32(kcb[ds], qf[ds], s1);
    }
    __builtin_amdgcn_s_setprio(0);

    // --- exp2 in place (lane-local rows, scale pre-folded) ---
    #pragma unroll
    for (int r = 0; r < 16; ++r) {
        s0[r] = __builtin_amdgcn_exp2f(s0[r]);
        s1[r] = __builtin_amdgcn_exp2f(s1[r]);
    }

    // --- pack P -> A-frags via cvt_pk + permlane32_swap ---
    bf16x8 pa[4];
    #pragma unroll
    for (int ks = 0; ks < 4; ++ks) {
        const int r0 = (ks & 1) * 8;
        unsigned int x0, y0, x1, y1;
        if (ks < 2) {
            x0 = cvtpk(s0[r0 + 0], s0[r0 + 1]);
            y0 = cvtpk(s0[r0 + 4], s0[r0 + 5]);
            x1 = cvtpk(s0[r0 + 2], s0[r0 + 3]);
            y1 = cvtpk(s0[r0 + 6], s0[r0 + 7]);
        } else {
            x0 = cvtpk(s1[r0 + 0], s1[r0 + 1]);
            y0 = cvtpk(s1[r0 + 4], s1[r0 + 5]);
            x1 = cvtpk(s1[r0 + 2], s1[r0 + 3]);
            y1 = cvtpk(s1[r0 + 6], s1[r0 + 7]);
        }
        pl32swap(x0, y0);
        pl32swap(x1, y1);
        union { unsigned int u[4]; bf16x8 v; } pu;
        pu.u[0] = x0; pu.u[1] = x1; pu.u[2] = y0; pu.u[3] = y1;
        pa[ks] = pu.v;
    }

    // --- PV + row-sum on the matrix pipe ---
    __builtin_amdgcn_s_setprio(1);
    #pragma unroll
    for (int ks = 0; ks < 4; ++ks) {
        accA = MFMA32(pa[ks], vfa[ks], accA);
        accB = MFMA32(pa[ks], vfb[ks], accB);
        accS = MFMA32(pa[ks], ones, accS);
    }
    __builtin_amdgcn_s_setprio(0);
}

__global__ __launch_bounds__(256, 2) void attn_kernel(const unsigned short* __restrict__ xb,
                                                      const unsigned short* __restrict__ xt,
                                                      unsigned short* __restrict__ ctxt) {
    const int bh = blockIdx.x;
    const int qt = blockIdx.y;
    const int tid = threadIdx.x;
    const int w = tid >> 6, lane = tid & 63;
    const int l31 = lane & 31, hh = lane >> 5;

    const char* xbB = (const char*)(xb + (size_t)bh * 131072);
    const char* xtB = (const char*)(xt + (size_t)bh * 131072);

    // --- Q hoist: B-frags for q-subtile st_q = qt*4 + w ---
    bf16x8 qf[4];
    {
        const char* qbase = xbB + (size_t)(qt * 4 + w) * 4096 + lane * 16;
        #pragma unroll
        for (int ds = 0; ds < 4; ++ds)
            qf[ds] = *(const bf16x8*)(qbase + ds * 1024);
    }

    // ones B-frag for the row-sum MFMA
    bf16x8 ones;
    #pragma unroll
    for (int i = 0; i < 8; ++i) ones[i] = (short)0x3F80;

    f32x16 accA, accB, accS;
    #pragma unroll
    for (int r = 0; r < 16; ++r) { accA[r] = 0.f; accB[r] = 0.f; accS[r] = 0.f; }

    // --- preload K(0) into buffer A ---
    bf16x8 kAa[4], kAb[4], kBa[4], kBb[4];
    {
        const char* kp = xbB + lane * 16;
        #pragma unroll
        for (int ds = 0; ds < 4; ++ds) {
            kAa[ds] = *(const bf16x8*)(kp + ds * 1024);
            kAb[ds] = *(const bf16x8*)(kp + 4096 + ds * 1024);
        }
    }

    for (int tt = 0; tt < 32; tt += 2) {
        attn_iter(tt,     xbB, xtB, lane, kAa, kAb, kBa, kBb, qf, ones, accA, accB, accS);
        attn_iter(tt + 1, xbB, xtB, lane, kBa, kBb, kAa, kAb, qf, ones, accA, accB, accS);
    }

    // --- epilogue: accS[r] is the rowsum for exactly accA[r]/accB[r]'s row ---
    const int b = bh >> 4, hd = bh & 15;
    const int mt = b * 16 + qt;
    unsigned short* tbase = ctxt + ((size_t)mt * 16 + hd) * 128 * 64;
    const int c80 = l31 >> 3, c81 = 4 + (l31 >> 3), ce = l31 & 7;
    #pragma unroll
    for (int r = 0; r < 16; ++r) {
        const float iv = 1.0f / accS[r];
        const int crow = (r & 3) + 8 * (r >> 2) + 4 * hh;
        const int rr = w * 32 + crow;
        unsigned short* rowp = tbase + rr * 64;
        const int sw = rr & 7;
        rowp[((c80 ^ sw) * 8) + ce] = f2bs(accA[r] * iv);
        rowp[((c81 ^ sw) * 8) + ce] = f2bs(accB[r] * iv);
    }
}

// ---------------------------------------------------------------------------
// Kernel 3: out = ctx @ W^T + b (unchanged).
// ---------------------------------------------------------------------------
__global__ __launch_bounds__(256) void proj_kernel(const unsigned short* __restrict__ ctxt,
                                                   const unsigned short* __restrict__ wbt,
                                                   const float* __restrict__ bias,
                                                   float* __restrict__ out) {
    const int ntb = blockIdx.x;
    const int mtb = blockIdx.y;
    const int tid = threadIdx.x;
    const int w = tid >> 6, lane = tid & 63;
    const int la = lane & 15, quad = lane >> 4;
    const int wm = (w >> 1) * 64, wn = (w & 1) * 64;

    __shared__ __align__(16) unsigned short As[2][8192];
    __shared__ __align__(16) unsigned short Bs[2][8192];

    const unsigned short* abase = ctxt + (size_t)mtb * 16 * 8192;
    const unsigned short* bbase = wbt  + (size_t)ntb * 16 * 8192;

    const int sw0 = ((quad)     ^ (la & 7)) * 8;
    const int sw1 = ((quad + 4) ^ (la & 7)) * 8;

    const f32x4 fzero = {0.f, 0.f, 0.f, 0.f};
    f32x4 acc[4][4];
    #pragma unroll
    for (int i = 0; i < 4; ++i)
        #pragma unroll
        for (int j = 0; j < 4; ++j) acc[i][j] = fzero;

    #pragma unroll
    for (int j = 0; j < 4; ++j) {
        const int fc = j * 256 + tid;
        GLOAD_LDS((const char*)abase + fc * 16, (char*)As[0] + fc * 16);
        GLOAD_LDS((const char*)bbase + fc * 16, (char*)Bs[0] + fc * 16);
    }
    __syncthreads();

    for (int kt = 0; kt < 16; ++kt) {
        if (kt < 15) {
            const char* asrc = (const char*)(abase + (kt + 1) * 8192);
            const char* bsrc = (const char*)(bbase + (kt + 1) * 8192);
            char* adst = (char*)As[(kt + 1) & 1];
            char* bdst = (char*)Bs[(kt + 1) & 1];
            #pragma unroll
            for (int j = 0; j < 4; ++j) {
                const int fc = j * 256 + tid;
                GLOAD_LDS(asrc + fc * 16, adst + fc * 16);
                GLOAD_LDS(bsrc + fc * 16, bdst + fc * 16);
            }
        }

        const unsigned short* Ab = As[kt & 1];
        const unsigned short* Bb = Bs[kt & 1];
        #pragma unroll
        for (int ks2 = 0; ks2 < 2; ++ks2) {
            const int sw = ks2 ? sw1 : sw0;
            bf16x8 af[4], bfr[4];
            #pragma unroll
            for (int mt = 0; mt < 4; ++mt) af[mt]  = *(const bf16x8*)&Ab[(wm + mt * 16 + la) * 64 + sw];
            #pragma unroll
            for (int nt = 0; nt < 4; ++nt) bfr[nt] = *(const bf16x8*)&Bb[(wn + nt * 16 + la) * 64 + sw];
            #pragma unroll
            for (int mt = 0; mt < 4; ++mt)
                #pragma unroll
                for (int nt = 0; nt < 4; ++nt)
                    acc[mt][nt] = __builtin_amdgcn_mfma_f32_16x16x32_bf16(af[mt], bfr[nt], acc[mt][nt], 0, 0, 0);
        }
        __syncthreads();
    }

    const int m0 = mtb * 128, n0 = ntb * 128;
    #pragma unroll
    for (int nt = 0; nt < 4; ++nt) {
        const int n = n0 + wn + nt * 16 + la;
        const float bv = bias[n];
        #pragma unroll
        for (int mt = 0; mt < 4; ++mt)
            #pragma unroll
            for (int r = 0; r < 4; ++r) {
                const int m = m0 + wm + mt * 16 + quad * 4 + r;
                out[(size_t)m * HDIM + n] = acc[mt][nt][r] + bv;
            }
    }
}

// ---------------------------------------------------------------------------
extern "C" void kernel_launch(void* const* d_in, const int* in_sizes, int n_in,
                              void* d_out, int out_size, void* d_ws, size_t ws_size,
                              hipStream_t stream) {
    const float* x    = (const float*)d_in[0];
    const float* W    = (const float*)d_in[1];
    const float* bias = (const float*)d_in[2];
    float* out = (float*)d_out;

    // ws layout (bytes): ctxt 8M | xb 8M | xt 8M | wbt 2M
    unsigned short* ctxt = (unsigned short*)d_ws;
    unsigned short* xbp  = (unsigned short*)((char*)d_ws + ( 8u << 20));
    unsigned short* xtp  = (unsigned short*)((char*)d_ws + (16u << 20));
    unsigned short* wbt  = (unsigned short*)((char*)d_ws + (24u << 20));

    prep_kernel<<<dim3(32, 32), 256, 0, stream>>>(x, W, xbp, xtp, wbt);
    attn_kernel<<<dim3(32, 16), 256, 0, stream>>>(xbp, xtp, ctxt);
    proj_kernel<<<dim3(8, 32), 256, 0, stream>>>(ctxt, wbt, bias, out);
}